// Round 1
// baseline (642.728 us; speedup 1.0000x reference)
//
#include <hip/hip_runtime.h>

// Multigrid PDE solver, 4 V-cycle-ish iterations + min/max normalize.
// u (4096x4096 f32) lives in d_out across iterations (final update is pointwise).

__global__ __launch_bounds__(256) void smooth_bc_kernel(
    const float* __restrict__ u, const float* __restrict__ A,
    float* __restrict__ r, int n)
{
    int x = blockIdx.x * 32 + (threadIdx.x & 31);
    int y = blockIdx.y * 8 + (threadIdx.x >> 5);
    if (x >= n || y >= n) return;
    float acc = 0.f;
#pragma unroll
    for (int dy = -1; dy <= 1; ++dy) {
#pragma unroll
        for (int dx = -1; dx <= 1; ++dx) {
            if (dy == 0 && dx == 0) continue;  // K center is zeroed
            int yy = y + dy, xx = x + dx;
            // padded-frame corners are zeroed in _bc
            bool corner = ((yy < 0) | (yy >= n)) & ((xx < 0) | (xx >= n));
            int cy = min(max(yy, 0), n - 1);
            int cx = min(max(xx, 0), n - 1);
            float v = corner ? 0.f : u[(size_t)cy * n + cx];
            acc += A[(dy + 1) * 3 + (dx + 1)] * v;
        }
    }
    r[(size_t)y * n + x] = acc;
}

__global__ __launch_bounds__(256) void restrict_kernel(
    const float* __restrict__ rin, float* __restrict__ rout, int nout)
{
    int x = blockIdx.x * 32 + (threadIdx.x & 31);
    int y = blockIdx.y * 8 + (threadIdx.x >> 5);
    if (x >= nout || y >= nout) return;
    int nin = nout * 2;
    const float* p0 = rin + (size_t)(2 * y) * nin + 2 * x;
    const float* p1 = p0 + nin;
    rout[(size_t)y * nout + x] = 0.25f * (p0[0] + p0[1] + p1[0] + p1[1]);
}

// e_out(level j, n x n) = Pe - smooth_zeropad(Pe)/diag + r_j/diag,
// Pe = nearest-2x-upsample of ec ((n/2)^2). scale_coarse: ec is r7 -> multiply by 1/diag.
__global__ __launch_bounds__(256) void up_kernel(
    const float* __restrict__ ec, const float* __restrict__ rj,
    const float* __restrict__ A, float* __restrict__ eo,
    int n, int scale_coarse)
{
    int x = blockIdx.x * 32 + (threadIdx.x & 31);
    int y = blockIdx.y * 8 + (threadIdx.x >> 5);
    if (x >= n || y >= n) return;
    float inv = 1.0f / A[4];
    float cs = scale_coarse ? inv : 1.0f;
    int nc = n >> 1;
    float pe[3][3];
#pragma unroll
    for (int dy = -1; dy <= 1; ++dy) {
#pragma unroll
        for (int dx = -1; dx <= 1; ++dx) {
            int yy = y + dy, xx = x + dx;
            float v = 0.f;  // zero padding for e
            if (yy >= 0 && yy < n && xx >= 0 && xx < n)
                v = ec[(size_t)(yy >> 1) * nc + (xx >> 1)] * cs;
            pe[dy + 1][dx + 1] = v;
        }
    }
    float sm = 0.f;
#pragma unroll
    for (int t = 0; t < 9; ++t) {
        if (t == 4) continue;
        sm += A[t] * pe[t / 3][t % 3];
    }
    eo[(size_t)y * n + x] = pe[1][1] - sm * inv + rj[(size_t)y * n + x] * inv;
}

// u_out = u_in - prol(e1) - r0/diag   (pointwise in u)
__global__ __launch_bounds__(256) void final_kernel(
    const float* __restrict__ uin, const float* __restrict__ e1,
    const float* __restrict__ r0, const float* __restrict__ A,
    float* __restrict__ uout, int n)
{
    int x = blockIdx.x * 32 + (threadIdx.x & 31);
    int y = blockIdx.y * 8 + (threadIdx.x >> 5);
    if (x >= n || y >= n) return;
    float inv = 1.0f / A[4];
    int nh = n >> 1;
    size_t i = (size_t)y * n + x;
    uout[i] = uin[i] - e1[(size_t)(y >> 1) * nh + (x >> 1)] - r0[i] * inv;
}

__global__ __launch_bounds__(256) void minmax_partial_kernel(
    const float* __restrict__ u, long long n2, float* __restrict__ partials)
{
    float mn = 3.402823466e+38f, mx = -3.402823466e+38f;
    for (long long i = (long long)blockIdx.x * blockDim.x + threadIdx.x; i < n2;
         i += (long long)gridDim.x * blockDim.x) {
        float v = u[i];
        mn = fminf(mn, v);
        mx = fmaxf(mx, v);
    }
#pragma unroll
    for (int off = 32; off > 0; off >>= 1) {
        mn = fminf(mn, __shfl_down(mn, off));
        mx = fmaxf(mx, __shfl_down(mx, off));
    }
    __shared__ float smn[4], smx[4];
    int lane = threadIdx.x & 63, wv = threadIdx.x >> 6;
    if (lane == 0) { smn[wv] = mn; smx[wv] = mx; }
    __syncthreads();
    if (threadIdx.x == 0) {
        mn = smn[0]; mx = smx[0];
        for (int w = 1; w < 4; ++w) { mn = fminf(mn, smn[w]); mx = fmaxf(mx, smx[w]); }
        partials[blockIdx.x * 2 + 0] = mn;
        partials[blockIdx.x * 2 + 1] = mx;
    }
}

__global__ __launch_bounds__(1024) void minmax_final_kernel(
    const float* __restrict__ partials, int nparts, float* __restrict__ mm)
{
    float mn = 3.402823466e+38f, mx = -3.402823466e+38f;
    for (int i = threadIdx.x; i < nparts; i += 1024) {
        mn = fminf(mn, partials[2 * i + 0]);
        mx = fmaxf(mx, partials[2 * i + 1]);
    }
#pragma unroll
    for (int off = 32; off > 0; off >>= 1) {
        mn = fminf(mn, __shfl_down(mn, off));
        mx = fmaxf(mx, __shfl_down(mx, off));
    }
    __shared__ float smn[16], smx[16];
    int lane = threadIdx.x & 63, wv = threadIdx.x >> 6;
    if (lane == 0) { smn[wv] = mn; smx[wv] = mx; }
    __syncthreads();
    if (threadIdx.x == 0) {
        mn = smn[0]; mx = smx[0];
        for (int w = 1; w < 16; ++w) { mn = fminf(mn, smn[w]); mx = fmaxf(mx, smx[w]); }
        mm[0] = mn;
        mm[1] = mx;
    }
}

__global__ __launch_bounds__(256) void normalize_kernel(
    float* __restrict__ u, const float* __restrict__ mm, long long n2)
{
    float mn = mm[0];
    float scale = 1.0f / (mm[1] - mm[0]);
    for (long long i = (long long)blockIdx.x * blockDim.x + threadIdx.x; i < n2;
         i += (long long)gridDim.x * blockDim.x) {
        u[i] = (u[i] - mn) * scale;
    }
}

extern "C" void kernel_launch(void* const* d_in, const int* in_sizes, int n_in,
                              void* d_out, int out_size, void* d_ws, size_t ws_size,
                              hipStream_t stream)
{
    const float* A  = (const float*)d_in[0];
    const float* u0 = (const float*)d_in[1];
    // d_in[2] is t; fixed at 4 by setup_inputs (graph capture needs a fixed structure).
    float* u  = (float*)d_out;
    float* ws = (float*)d_ws;

    const int n = 4096;
    size_t off = 0;
    float* r[8];
    r[0] = ws + off; off += (size_t)n * n;
    {
        int sz = n;
        for (int j = 1; j <= 7; ++j) { sz >>= 1; r[j] = ws + off; off += (size_t)sz * sz; }
    }
    float* eA = ws + off; off += (size_t)(n / 2) * (n / 2);
    float* eB = ws + off; off += (size_t)(n / 2) * (n / 2);
    float* partials = ws + off; off += 4096;
    float* mm = ws + off; off += 2;

    dim3 blk(256);
    auto grid2 = [](int m) { return dim3((m + 31) / 32, (m + 7) / 8); };

    for (int it = 0; it < 4; ++it) {
        const float* usrc = (it == 0) ? u0 : u;
        smooth_bc_kernel<<<grid2(n), blk, 0, stream>>>(usrc, A, r[0], n);
        int m = n;
        for (int j = 1; j <= 7; ++j) {
            m >>= 1;
            restrict_kernel<<<grid2(m), blk, 0, stream>>>(r[j - 1], r[j], m);
        }
        // coarse->fine correction chain; first level consumes r7 scaled by 1/diag
        up_kernel<<<grid2(64),   blk, 0, stream>>>(r[7], r[6], A, eA, 64,   1);
        up_kernel<<<grid2(128),  blk, 0, stream>>>(eA,   r[5], A, eB, 128,  0);
        up_kernel<<<grid2(256),  blk, 0, stream>>>(eB,   r[4], A, eA, 256,  0);
        up_kernel<<<grid2(512),  blk, 0, stream>>>(eA,   r[3], A, eB, 512,  0);
        up_kernel<<<grid2(1024), blk, 0, stream>>>(eB,   r[2], A, eA, 1024, 0);
        up_kernel<<<grid2(2048), blk, 0, stream>>>(eA,   r[1], A, eB, 2048, 0);
        final_kernel<<<grid2(n), blk, 0, stream>>>(usrc, eB, r[0], A, u, n);
    }

    long long n2 = (long long)n * n;
    minmax_partial_kernel<<<2048, 256, 0, stream>>>(u, n2, partials);
    minmax_final_kernel<<<1, 1024, 0, stream>>>(partials, 2048, mm);
    normalize_kernel<<<4096, 256, 0, stream>>>(u, mm, n2);
}

// Round 2
// 389.487 us; speedup vs baseline: 1.6502x; 1.6502x over previous
//
#include <hip/hip_runtime.h>

#define N 4096

// ---- fused smooth(bc(u)) + 2x2 restrict -> r1 (2048^2) ----
// r1[Y][X] = 0.25 * sum_{r,c in {0,1}} smooth(2Y+r, 2X+c)
//          = 0.25 * sum_{a,b in 4x4} w[a][b] * u_bc[2Y-1+a][2X-1+b]
// with w[r+i][c+j] += A'[i][j]  (A' = A with center zeroed)
__global__ __launch_bounds__(256) void smooth_restrict_kernel(
    const float* __restrict__ u, const float* __restrict__ Ag,
    float* __restrict__ r1)
{
    const int n = N, n1 = N / 2;
    int bx = blockIdx.x, by = blockIdx.y;      // tile 64x8 of r1
    int x0 = bx * 64, y0 = by * 8;
    int ux0 = 2 * x0, uy0 = 2 * y0;
    __shared__ __align__(16) float su[18][132]; // rows uy0-1..uy0+16, cols ux0-1..ux0+128
    int tid = threadIdx.x;
    for (int i = tid; i < 18 * 130; i += 256) {
        int row = i / 130, col = i - row * 130;
        int gy = uy0 - 1 + row, gx = ux0 - 1 + col;
        bool oy = (gy < 0) | (gy >= n);
        bool ox = (gx < 0) | (gx >= n);
        int cy = min(max(gy, 0), n - 1), cx = min(max(gx, 0), n - 1);
        float v = (oy & ox) ? 0.f : u[(size_t)cy * n + cx];
        su[row][col] = v;
    }
    float Ac[3][3];
#pragma unroll
    for (int i = 0; i < 9; ++i) Ac[i / 3][i % 3] = Ag[i];
    Ac[1][1] = 0.f;
    float w[4][4];
#pragma unroll
    for (int a = 0; a < 4; ++a)
#pragma unroll
        for (int b = 0; b < 4; ++b) w[a][b] = 0.f;
#pragma unroll
    for (int r = 0; r < 2; ++r)
#pragma unroll
        for (int c = 0; c < 2; ++c)
#pragma unroll
            for (int i = 0; i < 3; ++i)
#pragma unroll
                for (int j = 0; j < 3; ++j) w[r + i][c + j] += Ac[i][j];
    __syncthreads();

    int tx = tid & 31, ty = tid >> 5;  // outputs (y0+ty, x0+2tx), (y0+ty, x0+2tx+1)
    float p[4][6];
#pragma unroll
    for (int a = 0; a < 4; ++a) {
        const float* rowp = &su[2 * ty + a][4 * tx];
        float4 v4 = *(const float4*)rowp;
        float2 v2 = *(const float2*)(rowp + 4);
        p[a][0] = v4.x; p[a][1] = v4.y; p[a][2] = v4.z;
        p[a][3] = v4.w; p[a][4] = v2.x; p[a][5] = v2.y;
    }
    float o0 = 0.f, o1 = 0.f;
#pragma unroll
    for (int a = 0; a < 4; ++a)
#pragma unroll
        for (int b = 0; b < 4; ++b) {
            o0 += w[a][b] * p[a][b];
            o1 += w[a][b] * p[a][b + 2];
        }
    *(float2*)&r1[(size_t)(y0 + ty) * n1 + x0 + 2 * tx] = make_float2(0.25f * o0, 0.25f * o1);
}

// ---- one-shot restriction tree: r1 -> r2..r7 ----
__global__ __launch_bounds__(256) void multirestrict_kernel(
    const float* __restrict__ r1, float* __restrict__ r2, float* __restrict__ r3,
    float* __restrict__ r4, float* __restrict__ r5, float* __restrict__ r6,
    float* __restrict__ r7)
{
    const int n1 = 2048, n2 = 1024, n3 = 512, n4 = 256, n5 = 128, n6 = 64, n7 = 32;
    int BX = blockIdx.x, BY = blockIdx.y;  // 32x32 grid, 64x64 r1 patch each
    __shared__ __align__(16) float s2[32][36];
    __shared__ float s3[16][17];
    __shared__ float s4[8][9];
    __shared__ float s5[4][5];
    __shared__ float s6[2][3];
    int t = threadIdx.x;
    {
        int R = t >> 3, c8 = (t & 7) * 8;
        const float* base0 = &r1[(size_t)(BY * 64 + 2 * R) * n1 + BX * 64 + c8];
        const float* base1 = base0 + n1;
        float4 a0 = ((const float4*)base0)[0], a1 = ((const float4*)base0)[1];
        float4 b0 = ((const float4*)base1)[0], b1 = ((const float4*)base1)[1];
        float4 o;
        o.x = 0.25f * (a0.x + a0.y + b0.x + b0.y);
        o.y = 0.25f * (a0.z + a0.w + b0.z + b0.w);
        o.z = 0.25f * (a1.x + a1.y + b1.x + b1.y);
        o.w = 0.25f * (a1.z + a1.w + b1.z + b1.w);
        *(float4*)&r2[(size_t)(BY * 32 + R) * n2 + BX * 32 + (t & 7) * 4] = o;
        *(float4*)&s2[R][(t & 7) * 4] = o;
    }
    __syncthreads();
    {
        int y = t >> 4, x = t & 15;
        float v = 0.25f * (s2[2 * y][2 * x] + s2[2 * y][2 * x + 1] +
                           s2[2 * y + 1][2 * x] + s2[2 * y + 1][2 * x + 1]);
        r3[(size_t)(BY * 16 + y) * n3 + BX * 16 + x] = v;
        s3[y][x] = v;
    }
    __syncthreads();
    if (t < 64) {
        int y = t >> 3, x = t & 7;
        float v = 0.25f * (s3[2 * y][2 * x] + s3[2 * y][2 * x + 1] +
                           s3[2 * y + 1][2 * x] + s3[2 * y + 1][2 * x + 1]);
        r4[(size_t)(BY * 8 + y) * n4 + BX * 8 + x] = v;
        s4[y][x] = v;
    }
    __syncthreads();
    if (t < 16) {
        int y = t >> 2, x = t & 3;
        float v = 0.25f * (s4[2 * y][2 * x] + s4[2 * y][2 * x + 1] +
                           s4[2 * y + 1][2 * x] + s4[2 * y + 1][2 * x + 1]);
        r5[(size_t)(BY * 4 + y) * n5 + BX * 4 + x] = v;
        s5[y][x] = v;
    }
    __syncthreads();
    if (t < 4) {
        int y = t >> 1, x = t & 1;
        float v = 0.25f * (s5[2 * y][2 * x] + s5[2 * y][2 * x + 1] +
                           s5[2 * y + 1][2 * x] + s5[2 * y + 1][2 * x + 1]);
        r6[(size_t)(BY * 2 + y) * n6 + BX * 2 + x] = v;
        s6[y][x] = v;
    }
    __syncthreads();
    if (t == 0) {
        r7[(size_t)BY * n7 + BX] =
            0.25f * (s6[0][0] + s6[0][1] + s6[1][0] + s6[1][1]);
    }
}

// ---- coarse-to-fine correction: eo(n^2) = Pe - smooth_zeropad(Pe)/diag + rj/diag ----
// Pe = nearest-2x upsample of ec (n/2)^2 (times 1/diag when ec==r7).
__global__ __launch_bounds__(256) void up_kernel(
    const float* __restrict__ ec, const float* __restrict__ rj,
    const float* __restrict__ Ag, float* __restrict__ eo,
    int n, int scale_coarse)
{
    int nc = n >> 1;
    int tx = threadIdx.x & 15, ty = threadIdx.x >> 4;
    int X = blockIdx.x * 16 + tx, Y = blockIdx.y * 16 + ty;  // coarse coords, 2x2 fine out
    float Ac[3][3];
#pragma unroll
    for (int i = 0; i < 9; ++i) Ac[i / 3][i % 3] = Ag[i];
    float inv = 1.0f / Ac[1][1];
    Ac[1][1] = 0.f;
    float cs = scale_coarse ? inv : 1.f;
    float ecv[3][3];
#pragma unroll
    for (int i = 0; i < 3; ++i)
#pragma unroll
        for (int j = 0; j < 3; ++j) {
            int cy = Y - 1 + i, cx = X - 1 + j;
            bool ok = (cy >= 0) & (cy < nc) & (cx >= 0) & (cx < nc);
            ecv[i][j] = ok ? ec[(size_t)cy * nc + cx] * cs : 0.f;
        }
    float Pe[4][4];  // fine rows 2Y-1..2Y+2 -> coarse offsets {0,1,1,2}
#pragma unroll
    for (int i = 0; i < 4; ++i) {
        int ii = (i == 0) ? 0 : ((i == 3) ? 2 : 1);
#pragma unroll
        for (int j = 0; j < 4; ++j) {
            int jjm = (j == 0) ? 0 : ((j == 3) ? 2 : 1);
            Pe[i][j] = ecv[ii][jjm];
        }
    }
    float2 ra = *(const float2*)&rj[(size_t)(2 * Y) * n + 2 * X];
    float2 rb = *(const float2*)&rj[(size_t)(2 * Y + 1) * n + 2 * X];
    float rv[2][2] = {{ra.x, ra.y}, {rb.x, rb.y}};
    float o[2][2];
#pragma unroll
    for (int r = 0; r < 2; ++r)
#pragma unroll
        for (int c = 0; c < 2; ++c) {
            float sm = 0.f;
#pragma unroll
            for (int i = 0; i < 3; ++i)
#pragma unroll
                for (int j = 0; j < 3; ++j) sm += Ac[i][j] * Pe[r + i][c + j];
            o[r][c] = Pe[r + 1][c + 1] - sm * inv + rv[r][c] * inv;
        }
    *(float2*)&eo[(size_t)(2 * Y) * n + 2 * X] = make_float2(o[0][0], o[0][1]);
    *(float2*)&eo[(size_t)(2 * Y + 1) * n + 2 * X] = make_float2(o[1][0], o[1][1]);
}

// ---- fused: u_next = u - prol(e1) - smooth(bc(u))/diag ; optional minmax partials ----
template <bool WANTMM>
__global__ __launch_bounds__(256) void final_kernel_t(
    const float* __restrict__ u, const float* __restrict__ e1,
    const float* __restrict__ Ag, float* __restrict__ uo,
    float* __restrict__ partials)
{
    const int n = N, n1 = N / 2;
    int bx = blockIdx.x, by = blockIdx.y;  // tile 128x8 of u
    int ux0 = bx * 128, uy0 = by * 8;
    __shared__ __align__(16) float su[10][132];
    int tid = threadIdx.x;
    for (int i = tid; i < 10 * 130; i += 256) {
        int row = i / 130, col = i - row * 130;
        int gy = uy0 - 1 + row, gx = ux0 - 1 + col;
        bool oy = (gy < 0) | (gy >= n);
        bool ox = (gx < 0) | (gx >= n);
        int cy = min(max(gy, 0), n - 1), cx = min(max(gx, 0), n - 1);
        su[row][col] = (oy & ox) ? 0.f : u[(size_t)cy * n + cx];
    }
    float Ac[3][3];
#pragma unroll
    for (int i = 0; i < 9; ++i) Ac[i / 3][i % 3] = Ag[i];
    float inv = 1.0f / Ac[1][1];
    Ac[1][1] = 0.f;
    __syncthreads();

    int tx = tid & 31, ty = tid >> 5;  // outputs row uy0+ty, cols ux0+4tx..+3
    float p[3][6];
#pragma unroll
    for (int a = 0; a < 3; ++a) {
        const float* rowp = &su[ty + a][4 * tx];
        float4 v4 = *(const float4*)rowp;
        float2 v2 = *(const float2*)(rowp + 4);
        p[a][0] = v4.x; p[a][1] = v4.y; p[a][2] = v4.z;
        p[a][3] = v4.w; p[a][4] = v2.x; p[a][5] = v2.y;
    }
    int y = uy0 + ty;
    float2 ev = *(const float2*)&e1[(size_t)(y >> 1) * n1 + (ux0 >> 1) + 2 * tx];
    float out[4];
#pragma unroll
    for (int c = 0; c < 4; ++c) {
        float sm = 0.f;
#pragma unroll
        for (int i = 0; i < 3; ++i)
#pragma unroll
            for (int j = 0; j < 3; ++j) sm += Ac[i][j] * p[i][c + j];
        float e = (c < 2) ? ev.x : ev.y;
        out[c] = p[1][c + 1] - e - sm * inv;
    }
    *(float4*)&uo[(size_t)y * n + ux0 + 4 * tx] =
        make_float4(out[0], out[1], out[2], out[3]);

    if (WANTMM) {
        float mn = fminf(fminf(out[0], out[1]), fminf(out[2], out[3]));
        float mx = fmaxf(fmaxf(out[0], out[1]), fmaxf(out[2], out[3]));
#pragma unroll
        for (int off = 32; off > 0; off >>= 1) {
            mn = fminf(mn, __shfl_down(mn, off));
            mx = fmaxf(mx, __shfl_down(mx, off));
        }
        __shared__ float smn[4], smx[4];
        int lane = tid & 63, wv = tid >> 6;
        if (lane == 0) { smn[wv] = mn; smx[wv] = mx; }
        __syncthreads();
        if (tid == 0) {
            mn = smn[0]; mx = smx[0];
            for (int wq = 1; wq < 4; ++wq) { mn = fminf(mn, smn[wq]); mx = fmaxf(mx, smx[wq]); }
            int bid = blockIdx.y * gridDim.x + blockIdx.x;
            partials[2 * bid] = mn;
            partials[2 * bid + 1] = mx;
        }
    }
}

__global__ __launch_bounds__(1024) void minmax_final_kernel(
    const float* __restrict__ partials, float* __restrict__ mm)
{
    float mn = 3.402823466e+38f, mx = -3.402823466e+38f;
    for (int i = threadIdx.x; i < 16384; i += 1024) {
        mn = fminf(mn, partials[2 * i]);
        mx = fmaxf(mx, partials[2 * i + 1]);
    }
#pragma unroll
    for (int off = 32; off > 0; off >>= 1) {
        mn = fminf(mn, __shfl_down(mn, off));
        mx = fmaxf(mx, __shfl_down(mx, off));
    }
    __shared__ float smn[16], smx[16];
    int lane = threadIdx.x & 63, wv = threadIdx.x >> 6;
    if (lane == 0) { smn[wv] = mn; smx[wv] = mx; }
    __syncthreads();
    if (threadIdx.x == 0) {
        mn = smn[0]; mx = smx[0];
        for (int w = 1; w < 16; ++w) { mn = fminf(mn, smn[w]); mx = fmaxf(mx, smx[w]); }
        mm[0] = mn;
        mm[1] = mx;
    }
}

__global__ __launch_bounds__(256) void normalize_kernel(
    float* __restrict__ u, const float* __restrict__ mm)
{
    size_t i = ((size_t)blockIdx.x * 256 + threadIdx.x) * 4;
    float mn = mm[0];
    float sc = 1.0f / (mm[1] - mm[0]);
    float4 v = *(float4*)&u[i];
    v.x = (v.x - mn) * sc;
    v.y = (v.y - mn) * sc;
    v.z = (v.z - mn) * sc;
    v.w = (v.w - mn) * sc;
    *(float4*)&u[i] = v;
}

extern "C" void kernel_launch(void* const* d_in, const int* in_sizes, int n_in,
                              void* d_out, int out_size, void* d_ws, size_t ws_size,
                              hipStream_t stream)
{
    const float* A  = (const float*)d_in[0];
    const float* u0 = (const float*)d_in[1];
    float* uout = (float*)d_out;
    float* ws = (float*)d_ws;

    size_t off = 0;
    float* r1 = ws + off; off += 2048ull * 2048;
    float* r2 = ws + off; off += 1024ull * 1024;
    float* r3 = ws + off; off += 512ull * 512;
    float* r4 = ws + off; off += 256ull * 256;
    float* r5 = ws + off; off += 128ull * 128;
    float* r6 = ws + off; off += 64ull * 64;
    float* r7 = ws + off; off += 32ull * 32;
    float* eA = ws + off; off += 2048ull * 2048;
    float* eB = ws + off; off += 2048ull * 2048;
    float* uA = ws + off; off += 4096ull * 4096;
    float* partials = ws + off; off += 32768;
    float* mm = ws + off; off += 2;

    dim3 blk(256);
    for (int it = 0; it < 4; ++it) {
        const float* us = (it == 0) ? u0 : ((it == 2) ? uout : uA);
        float* dst = (it & 1) ? uout : uA;
        smooth_restrict_kernel<<<dim3(32, 256), blk, 0, stream>>>(us, A, r1);
        multirestrict_kernel<<<dim3(32, 32), blk, 0, stream>>>(r1, r2, r3, r4, r5, r6, r7);
        up_kernel<<<dim3(2, 2),   blk, 0, stream>>>(r7, r6, A, eA, 64, 1);
        up_kernel<<<dim3(4, 4),   blk, 0, stream>>>(eA, r5, A, eB, 128, 0);
        up_kernel<<<dim3(8, 8),   blk, 0, stream>>>(eB, r4, A, eA, 256, 0);
        up_kernel<<<dim3(16, 16), blk, 0, stream>>>(eA, r3, A, eB, 512, 0);
        up_kernel<<<dim3(32, 32), blk, 0, stream>>>(eB, r2, A, eA, 1024, 0);
        up_kernel<<<dim3(64, 64), blk, 0, stream>>>(eA, r1, A, eB, 2048, 0);
        if (it == 3)
            final_kernel_t<true><<<dim3(32, 512), blk, 0, stream>>>(us, eB, A, dst, partials);
        else
            final_kernel_t<false><<<dim3(32, 512), blk, 0, stream>>>(us, eB, A, dst, partials);
    }
    minmax_final_kernel<<<1, 1024, 0, stream>>>(partials, mm);
    normalize_kernel<<<16384, 256, 0, stream>>>(uout, mm);
}

// Round 3
// 379.857 us; speedup vs baseline: 1.6920x; 1.0254x over previous
//
#include <hip/hip_runtime.h>

#define N 4096

__device__ __forceinline__ void load_A(const float* __restrict__ Ag,
                                       float Ac[3][3], float& inv)
{
#pragma unroll
    for (int i = 0; i < 9; ++i) Ac[i / 3][i % 3] = Ag[i];
    inv = 1.0f / Ac[1][1];
    Ac[1][1] = 0.f;
}

// ---- fused smooth(bc(u))+restrict -> r1, plus full restriction tree r2..r7 ----
// Each block: 64x64 tile of r1 (u patch 130x130 streamed in 8 chunks of 18 rows),
// kept in LDS, then reduced to r2..r7 (one r7 element per block).
__global__ __launch_bounds__(256) void smooth_tree_kernel(
    const float* __restrict__ u, const float* __restrict__ Ag,
    float* __restrict__ r1, float* __restrict__ r2, float* __restrict__ r3,
    float* __restrict__ r4, float* __restrict__ r5, float* __restrict__ r6,
    float* __restrict__ r7)
{
    const int n = N;
    int bx = blockIdx.x, by = blockIdx.y;
    __shared__ __align__(16) float su[18][132];
    __shared__ __align__(16) float sr1[64][68];
    __shared__ __align__(16) float s2[32][36];
    __shared__ float s3[16][17];
    __shared__ float s4[8][9];
    __shared__ float s5[4][5];
    __shared__ float s6[2][3];
    int t = threadIdx.x;
    float Ac[3][3], inv;
    load_A(Ag, Ac, inv);
    // combined 4x4 smooth+restrict weights
    float w[4][4];
#pragma unroll
    for (int a = 0; a < 4; ++a)
#pragma unroll
        for (int b = 0; b < 4; ++b) w[a][b] = 0.f;
#pragma unroll
    for (int r = 0; r < 2; ++r)
#pragma unroll
        for (int c = 0; c < 2; ++c)
#pragma unroll
            for (int i = 0; i < 3; ++i)
#pragma unroll
                for (int j = 0; j < 3; ++j) w[r + i][c + j] += Ac[i][j];

    int ty = t >> 5;            // 8 r1 rows per chunk
    int txo = (t & 31) * 2;     // 2 r1 cols per thread
#pragma unroll 1
    for (int c = 0; c < 8; ++c) {
        int uy0 = 128 * by + 16 * c - 1, ux0 = 128 * bx - 1;
        bool safe = (uy0 >= 0) & (uy0 + 18 <= n) & (ux0 >= 0) & (ux0 + 130 <= n);
        if (safe) {
            const float* ub = &u[(size_t)uy0 * n + ux0];
            for (int i = t; i < 18 * 130; i += 256) {
                int row = i / 130, col = i - row * 130;
                su[row][col] = ub[(size_t)row * n + col];
            }
        } else {
            for (int i = t; i < 18 * 130; i += 256) {
                int row = i / 130, col = i - row * 130;
                int gy = uy0 + row, gx = ux0 + col;
                bool oy = (gy < 0) | (gy >= n);
                bool ox = (gx < 0) | (gx >= n);
                int cy = min(max(gy, 0), n - 1), cx = min(max(gx, 0), n - 1);
                su[row][col] = (oy & ox) ? 0.f : u[(size_t)cy * n + cx];
            }
        }
        __syncthreads();
        float o0 = 0.f, o1 = 0.f;
#pragma unroll
        for (int a = 0; a < 4; ++a) {
            const float* rp = &su[2 * ty + a][2 * txo];
            float4 v4 = *(const float4*)rp;
            float2 v2 = *(const float2*)(rp + 4);
            float v[6] = {v4.x, v4.y, v4.z, v4.w, v2.x, v2.y};
#pragma unroll
            for (int b = 0; b < 4; ++b) {
                o0 += w[a][b] * v[b];
                o1 += w[a][b] * v[b + 2];
            }
        }
        o0 *= 0.25f; o1 *= 0.25f;
        int gr = 64 * by + 8 * c + ty;
        *(float2*)&r1[(size_t)gr * 2048 + 64 * bx + txo] = make_float2(o0, o1);
        *(float2*)&sr1[8 * c + ty][txo] = make_float2(o0, o1);
        __syncthreads();
    }
    // ---- restriction tree from sr1 ----
    {
        int y = t >> 3, x4 = (t & 7) * 4;
        float4 o;
        float* po = &o.x;
#pragma unroll
        for (int k = 0; k < 4; ++k) {
            int x = x4 + k;
            po[k] = 0.25f * (sr1[2 * y][2 * x] + sr1[2 * y][2 * x + 1] +
                             sr1[2 * y + 1][2 * x] + sr1[2 * y + 1][2 * x + 1]);
        }
        *(float4*)&r2[(size_t)(32 * by + y) * 1024 + 32 * bx + x4] = o;
        *(float4*)&s2[y][x4] = o;
    }
    __syncthreads();
    {
        int y = t >> 4, x = t & 15;
        float v = 0.25f * (s2[2 * y][2 * x] + s2[2 * y][2 * x + 1] +
                           s2[2 * y + 1][2 * x] + s2[2 * y + 1][2 * x + 1]);
        r3[(size_t)(16 * by + y) * 512 + 16 * bx + x] = v;
        s3[y][x] = v;
    }
    __syncthreads();
    if (t < 64) {
        int y = t >> 3, x = t & 7;
        float v = 0.25f * (s3[2 * y][2 * x] + s3[2 * y][2 * x + 1] +
                           s3[2 * y + 1][2 * x] + s3[2 * y + 1][2 * x + 1]);
        r4[(size_t)(8 * by + y) * 256 + 8 * bx + x] = v;
        s4[y][x] = v;
    }
    __syncthreads();
    if (t < 16) {
        int y = t >> 2, x = t & 3;
        float v = 0.25f * (s4[2 * y][2 * x] + s4[2 * y][2 * x + 1] +
                           s4[2 * y + 1][2 * x] + s4[2 * y + 1][2 * x + 1]);
        r5[(size_t)(4 * by + y) * 128 + 4 * bx + x] = v;
        s5[y][x] = v;
    }
    __syncthreads();
    if (t < 4) {
        int y = t >> 1, x = t & 1;
        float v = 0.25f * (s5[2 * y][2 * x] + s5[2 * y][2 * x + 1] +
                           s5[2 * y + 1][2 * x] + s5[2 * y + 1][2 * x + 1]);
        r6[(size_t)(2 * by + y) * 64 + 2 * bx + x] = v;
        s6[y][x] = v;
    }
    __syncthreads();
    if (t == 0) {
        r7[(size_t)by * 32 + bx] =
            0.25f * (s6[0][0] + s6[0][1] + s6[1][0] + s6[1][1]);
    }
}

// ---- fused coarse up-chain: r7..r3 -> e@512 (patch recompute per block) ----
__global__ __launch_bounds__(256) void coarse_up_kernel(
    const float* __restrict__ r7, const float* __restrict__ r6,
    const float* __restrict__ r5, const float* __restrict__ r4,
    const float* __restrict__ r3, const float* __restrict__ Ag,
    float* __restrict__ e512)
{
    int bx = blockIdx.x, by = blockIdx.y;  // 16x16 grid, 32x32 of e512 each
    int t = threadIdx.x;
    __shared__ float s7[32][33];
    __shared__ float s64[64][65];
    __shared__ float s128[11][12];
    __shared__ float s256[18][19];
    float Ac[3][3], inv;
    load_A(Ag, Ac, inv);
    for (int i = t; i < 1024; i += 256) s7[i >> 5][i & 31] = r7[i] * inv;
    __syncthreads();
    // full e64
    for (int i = t; i < 4096; i += 256) {
        int y = i >> 6, x = i & 63;
        float ctr = s7[y >> 1][x >> 1];
        float sm = 0.f;
#pragma unroll
        for (int dy = -1; dy <= 1; ++dy)
#pragma unroll
            for (int dx = -1; dx <= 1; ++dx) {
                if (dy == 0 && dx == 0) continue;
                int yy = y + dy, xx = x + dx;
                float pe = 0.f;
                if (yy >= 0 && yy < 64 && xx >= 0 && xx < 64) pe = s7[yy >> 1][xx >> 1];
                sm += Ac[dy + 1][dx + 1] * pe;
            }
        s64[y][x] = ctr - sm * inv + r6[i] * inv;
    }
    __syncthreads();
    // e128 patch 11x11
    int R1 = 8 * by - 2, C1 = 8 * bx - 2;
    if (t < 121) {
        int pr = t / 11, pc = t % 11;
        int gy = R1 + pr, gx = C1 + pc;
        if (gy >= 0 && gy < 128 && gx >= 0 && gx < 128) {
            float ctr = s64[gy >> 1][gx >> 1];
            float sm = 0.f;
#pragma unroll
            for (int dy = -1; dy <= 1; ++dy)
#pragma unroll
                for (int dx = -1; dx <= 1; ++dx) {
                    if (dy == 0 && dx == 0) continue;
                    int yy = gy + dy, xx = gx + dx;
                    float pe = 0.f;
                    if (yy >= 0 && yy < 128 && xx >= 0 && xx < 128) pe = s64[yy >> 1][xx >> 1];
                    sm += Ac[dy + 1][dx + 1] * pe;
                }
            s128[pr][pc] = ctr - sm * inv + r5[(size_t)gy * 128 + gx] * inv;
        }
    }
    __syncthreads();
    // e256 patch 18x18
    int R2l = 16 * by - 1, C2l = 16 * bx - 1;
    for (int i = t; i < 324; i += 256) {
        int pr = i / 18, pc = i % 18;
        int gy = R2l + pr, gx = C2l + pc;
        if (gy >= 0 && gy < 256 && gx >= 0 && gx < 256) {
            float ctr = s128[(gy >> 1) - R1][(gx >> 1) - C1];
            float sm = 0.f;
#pragma unroll
            for (int dy = -1; dy <= 1; ++dy)
#pragma unroll
                for (int dx = -1; dx <= 1; ++dx) {
                    if (dy == 0 && dx == 0) continue;
                    int yy = gy + dy, xx = gx + dx;
                    float pe = 0.f;
                    if (yy >= 0 && yy < 256 && xx >= 0 && xx < 256)
                        pe = s128[(yy >> 1) - R1][(xx >> 1) - C1];
                    sm += Ac[dy + 1][dx + 1] * pe;
                }
            s256[pr][pc] = ctr - sm * inv + r4[(size_t)gy * 256 + gx] * inv;
        }
    }
    __syncthreads();
    // e512 tile 32x32
#pragma unroll
    for (int k = 0; k < 4; ++k) {
        int idx = t + 256 * k;
        int y = 32 * by + (idx >> 5), x = 32 * bx + (idx & 31);
        float ctr = s256[(y >> 1) - R2l][(x >> 1) - C2l];
        float sm = 0.f;
#pragma unroll
        for (int dy = -1; dy <= 1; ++dy)
#pragma unroll
            for (int dx = -1; dx <= 1; ++dx) {
                if (dy == 0 && dx == 0) continue;
                int yy = y + dy, xx = x + dx;
                float pe = 0.f;
                if (yy >= 0 && yy < 512 && xx >= 0 && xx < 512)
                    pe = s256[(yy >> 1) - R2l][(xx >> 1) - C2l];
                sm += Ac[dy + 1][dx + 1] * pe;
            }
        e512[(size_t)y * 512 + x] = ctr - sm * inv + r3[(size_t)y * 512 + x] * inv;
    }
}

// ---- fused: e512 -> e1024 patch -> e2048 tile -> u update (+ minmax partials) ----
template <bool WANTMM>
__global__ __launch_bounds__(256) void final_fused_kernel(
    const float* __restrict__ u, const float* __restrict__ e512,
    const float* __restrict__ r2, const float* __restrict__ r1,
    const float* __restrict__ Ag, float* __restrict__ uo,
    float* __restrict__ partials)
{
    const int n = N;
    int bx = blockIdx.x, by = blockIdx.y;  // grid (32,256): u tile 128x16
    int t = threadIdx.x;
    __shared__ __align__(16) float su[18][132];
    __shared__ float s512[4][20];
    __shared__ float s1024[6][36];
    __shared__ float s2048[8][68];
    float Ac[3][3], inv;
    load_A(Ag, Ac, inv);
    int uy0 = 16 * by - 1, ux0 = 128 * bx - 1;
    bool safe = (uy0 >= 0) & (uy0 + 18 <= n) & (ux0 >= 0) & (ux0 + 130 <= n);
    if (safe) {
        const float* ub = &u[(size_t)uy0 * n + ux0];
        for (int i = t; i < 18 * 130; i += 256) {
            int row = i / 130, col = i - row * 130;
            su[row][col] = ub[(size_t)row * n + col];
        }
    } else {
        for (int i = t; i < 18 * 130; i += 256) {
            int row = i / 130, col = i - row * 130;
            int gy = uy0 + row, gx = ux0 + col;
            bool oy = (gy < 0) | (gy >= n);
            bool ox = (gx < 0) | (gx >= n);
            int cy = min(max(gy, 0), n - 1), cx = min(max(gx, 0), n - 1);
            su[row][col] = (oy & ox) ? 0.f : u[(size_t)cy * n + cx];
        }
    }
    int S5r = 2 * by - 1, S5c = 16 * bx - 1;
    if (t < 72) {
        int pr = t / 18, pc = t % 18;
        int gy = S5r + pr, gx = S5c + pc;
        if (gy >= 0 && gy < 512 && gx >= 0 && gx < 512)
            s512[pr][pc] = e512[(size_t)gy * 512 + gx];
    }
    __syncthreads();
    // e1024 patch 6x34
    int R10 = 4 * by - 1, C10 = 32 * bx - 1;
    if (t < 204) {
        int pr = t / 34, pc = t % 34;
        int gy = R10 + pr, gx = C10 + pc;
        if (gy >= 0 && gy < 1024 && gx >= 0 && gx < 1024) {
            float ctr = s512[(gy >> 1) - S5r][(gx >> 1) - S5c];
            float sm = 0.f;
#pragma unroll
            for (int dy = -1; dy <= 1; ++dy)
#pragma unroll
                for (int dx = -1; dx <= 1; ++dx) {
                    if (dy == 0 && dx == 0) continue;
                    int yy = gy + dy, xx = gx + dx;
                    float pe = 0.f;
                    if (yy >= 0 && yy < 1024 && xx >= 0 && xx < 1024)
                        pe = s512[(yy >> 1) - S5r][(xx >> 1) - S5c];
                    sm += Ac[dy + 1][dx + 1] * pe;
                }
            s1024[pr][pc] = ctr - sm * inv + r2[(size_t)gy * 1024 + gx] * inv;
        }
    }
    __syncthreads();
    // e2048 tile 8x64
    int E2r = 8 * by, E2c = 64 * bx;
    for (int i = t; i < 512; i += 256) {
        int pr = i >> 6, pc = i & 63;
        int gy = E2r + pr, gx = E2c + pc;
        float ctr = s1024[(gy >> 1) - R10][(gx >> 1) - C10];
        float sm = 0.f;
#pragma unroll
        for (int dy = -1; dy <= 1; ++dy)
#pragma unroll
            for (int dx = -1; dx <= 1; ++dx) {
                if (dy == 0 && dx == 0) continue;
                int yy = gy + dy, xx = gx + dx;
                float pe = 0.f;
                if (yy >= 0 && yy < 2048 && xx >= 0 && xx < 2048)
                    pe = s1024[(yy >> 1) - R10][(xx >> 1) - C10];
                sm += Ac[dy + 1][dx + 1] * pe;
            }
        s2048[pr][pc] = ctr - sm * inv + r1[(size_t)gy * 2048 + gx] * inv;
    }
    __syncthreads();
    // u update
    int txx = t & 31, tyy = t >> 5;
    float mn = 3.402823466e+38f, mx = -3.402823466e+38f;
#pragma unroll
    for (int rr = 0; rr < 2; ++rr) {
        int yl = tyy + 8 * rr;
        int y = 16 * by + yl;
        float p[3][6];
#pragma unroll
        for (int a = 0; a < 3; ++a) {
            const float* rp = &su[yl + a][4 * txx];
            float4 v4 = *(const float4*)rp;
            float2 v2 = *(const float2*)(rp + 4);
            p[a][0] = v4.x; p[a][1] = v4.y; p[a][2] = v4.z;
            p[a][3] = v4.w; p[a][4] = v2.x; p[a][5] = v2.y;
        }
        float out[4];
#pragma unroll
        for (int cc = 0; cc < 4; ++cc) {
            float sm = 0.f;
#pragma unroll
            for (int i2 = 0; i2 < 3; ++i2)
#pragma unroll
                for (int j = 0; j < 3; ++j) sm += Ac[i2][j] * p[i2][cc + j];
            float e = s2048[yl >> 1][(4 * txx + cc) >> 1];
            out[cc] = p[1][cc + 1] - e - sm * inv;
        }
        *(float4*)&uo[(size_t)y * n + 128 * bx + 4 * txx] =
            make_float4(out[0], out[1], out[2], out[3]);
        if (WANTMM) {
            mn = fminf(mn, fminf(fminf(out[0], out[1]), fminf(out[2], out[3])));
            mx = fmaxf(mx, fmaxf(fmaxf(out[0], out[1]), fmaxf(out[2], out[3])));
        }
    }
    if (WANTMM) {
#pragma unroll
        for (int off = 32; off > 0; off >>= 1) {
            mn = fminf(mn, __shfl_down(mn, off));
            mx = fmaxf(mx, __shfl_down(mx, off));
        }
        __shared__ float smn[4], smx[4];
        int lane = t & 63, wv = t >> 6;
        if (lane == 0) { smn[wv] = mn; smx[wv] = mx; }
        __syncthreads();
        if (t == 0) {
            mn = smn[0]; mx = smx[0];
            for (int wq = 1; wq < 4; ++wq) { mn = fminf(mn, smn[wq]); mx = fmaxf(mx, smx[wq]); }
            int bid = by * 32 + bx;
            partials[2 * bid] = mn;
            partials[2 * bid + 1] = mx;
        }
    }
}

__global__ __launch_bounds__(1024) void minmax_final_kernel(
    const float* __restrict__ partials, float* __restrict__ mm)
{
    float mn = 3.402823466e+38f, mx = -3.402823466e+38f;
    for (int i = threadIdx.x; i < 8192; i += 1024) {
        mn = fminf(mn, partials[2 * i]);
        mx = fmaxf(mx, partials[2 * i + 1]);
    }
#pragma unroll
    for (int off = 32; off > 0; off >>= 1) {
        mn = fminf(mn, __shfl_down(mn, off));
        mx = fmaxf(mx, __shfl_down(mx, off));
    }
    __shared__ float smn[16], smx[16];
    int lane = threadIdx.x & 63, wv = threadIdx.x >> 6;
    if (lane == 0) { smn[wv] = mn; smx[wv] = mx; }
    __syncthreads();
    if (threadIdx.x == 0) {
        mn = smn[0]; mx = smx[0];
        for (int w = 1; w < 16; ++w) { mn = fminf(mn, smn[w]); mx = fmaxf(mx, smx[w]); }
        mm[0] = mn;
        mm[1] = mx;
    }
}

__global__ __launch_bounds__(256) void normalize_kernel(
    float* __restrict__ u, const float* __restrict__ mm)
{
    size_t i = ((size_t)blockIdx.x * 256 + threadIdx.x) * 4;
    float mn = mm[0];
    float sc = 1.0f / (mm[1] - mm[0]);
    float4 v = *(float4*)&u[i];
    v.x = (v.x - mn) * sc;
    v.y = (v.y - mn) * sc;
    v.z = (v.z - mn) * sc;
    v.w = (v.w - mn) * sc;
    *(float4*)&u[i] = v;
}

extern "C" void kernel_launch(void* const* d_in, const int* in_sizes, int n_in,
                              void* d_out, int out_size, void* d_ws, size_t ws_size,
                              hipStream_t stream)
{
    const float* A  = (const float*)d_in[0];
    const float* u0 = (const float*)d_in[1];
    float* uout = (float*)d_out;
    float* ws = (float*)d_ws;

    size_t off = 0;
    float* r1 = ws + off; off += 2048ull * 2048;
    float* r2 = ws + off; off += 1024ull * 1024;
    float* r3 = ws + off; off += 512ull * 512;
    float* r4 = ws + off; off += 256ull * 256;
    float* r5 = ws + off; off += 128ull * 128;
    float* r6 = ws + off; off += 64ull * 64;
    float* r7 = ws + off; off += 32ull * 32;
    float* e5 = ws + off; off += 512ull * 512;
    float* uA = ws + off; off += 4096ull * 4096;
    float* partials = ws + off; off += 16384;
    float* mm = ws + off; off += 2;

    dim3 blk(256);
    for (int it = 0; it < 4; ++it) {
        const float* us = (it == 0) ? u0 : ((it == 2) ? uout : uA);
        float* dst = (it & 1) ? uout : uA;
        smooth_tree_kernel<<<dim3(32, 32), blk, 0, stream>>>(us, A, r1, r2, r3, r4, r5, r6, r7);
        coarse_up_kernel<<<dim3(16, 16), blk, 0, stream>>>(r7, r6, r5, r4, r3, A, e5);
        if (it == 3)
            final_fused_kernel<true><<<dim3(32, 256), blk, 0, stream>>>(us, e5, r2, r1, A, dst, partials);
        else
            final_fused_kernel<false><<<dim3(32, 256), blk, 0, stream>>>(us, e5, r2, r1, A, dst, partials);
    }
    minmax_final_kernel<<<1, 1024, 0, stream>>>(partials, mm);
    normalize_kernel<<<16384, 256, 0, stream>>>(uout, mm);
}

// Round 4
// 347.440 us; speedup vs baseline: 1.8499x; 1.0933x over previous
//
#include <hip/hip_runtime.h>

#define N 4096

__device__ __forceinline__ void load_A(const float* __restrict__ Ag,
                                       float Ac[3][3], float& inv)
{
#pragma unroll
    for (int i = 0; i < 9; ++i) Ac[i / 3][i % 3] = Ag[i];
    inv = 1.0f / Ac[1][1];
    Ac[1][1] = 0.f;
}

// ---- fused smooth(bc(u)) + 2x2 restrict -> r1 (2048^2) ----
__global__ __launch_bounds__(256) void smooth_restrict_kernel(
    const float* __restrict__ u, const float* __restrict__ Ag,
    float* __restrict__ r1)
{
    const int n = N, n1 = N / 2;
    int bx = blockIdx.x, by = blockIdx.y;      // tile 64x8 of r1
    int x0 = bx * 64, y0 = by * 8;
    int ux0 = 2 * x0, uy0 = 2 * y0;
    __shared__ __align__(16) float su[18][132];
    int tid = threadIdx.x;
    {
        int uys = uy0 - 1, uxs = ux0 - 1;
        bool safe = (uys >= 0) & (uys + 18 <= n) & (uxs >= 0) & (uxs + 130 <= n);
        if (safe) {
            const float* ub = &u[(size_t)uys * n + uxs];
            for (int i = tid; i < 18 * 130; i += 256) {
                int row = i / 130, col = i - row * 130;
                su[row][col] = ub[(size_t)row * n + col];
            }
        } else {
            for (int i = tid; i < 18 * 130; i += 256) {
                int row = i / 130, col = i - row * 130;
                int gy = uys + row, gx = uxs + col;
                bool oy = (gy < 0) | (gy >= n);
                bool ox = (gx < 0) | (gx >= n);
                int cy = min(max(gy, 0), n - 1), cx = min(max(gx, 0), n - 1);
                su[row][col] = (oy & ox) ? 0.f : u[(size_t)cy * n + cx];
            }
        }
    }
    float Ac[3][3], inv;
    load_A(Ag, Ac, inv);
    float w[4][4];
#pragma unroll
    for (int a = 0; a < 4; ++a)
#pragma unroll
        for (int b = 0; b < 4; ++b) w[a][b] = 0.f;
#pragma unroll
    for (int r = 0; r < 2; ++r)
#pragma unroll
        for (int c = 0; c < 2; ++c)
#pragma unroll
            for (int i = 0; i < 3; ++i)
#pragma unroll
                for (int j = 0; j < 3; ++j) w[r + i][c + j] += Ac[i][j];
    __syncthreads();

    int tx = tid & 31, ty = tid >> 5;
    float p[4][6];
#pragma unroll
    for (int a = 0; a < 4; ++a) {
        const float* rowp = &su[2 * ty + a][4 * tx];
        float4 v4 = *(const float4*)rowp;
        float2 v2 = *(const float2*)(rowp + 4);
        p[a][0] = v4.x; p[a][1] = v4.y; p[a][2] = v4.z;
        p[a][3] = v4.w; p[a][4] = v2.x; p[a][5] = v2.y;
    }
    float o0 = 0.f, o1 = 0.f;
#pragma unroll
    for (int a = 0; a < 4; ++a)
#pragma unroll
        for (int b = 0; b < 4; ++b) {
            o0 += w[a][b] * p[a][b];
            o1 += w[a][b] * p[a][b + 2];
        }
    *(float2*)&r1[(size_t)(y0 + ty) * n1 + x0 + 2 * tx] = make_float2(0.25f * o0, 0.25f * o1);
}

// ---- one-shot restriction tree: r1 -> r2..r7 ----
__global__ __launch_bounds__(256) void multirestrict_kernel(
    const float* __restrict__ r1, float* __restrict__ r2, float* __restrict__ r3,
    float* __restrict__ r4, float* __restrict__ r5, float* __restrict__ r6,
    float* __restrict__ r7)
{
    const int n1 = 2048, n2 = 1024, n3 = 512, n4 = 256, n5 = 128, n6 = 64, n7 = 32;
    int BX = blockIdx.x, BY = blockIdx.y;  // 32x32 grid, 64x64 r1 patch each
    __shared__ __align__(16) float s2[32][36];
    __shared__ float s3[16][17];
    __shared__ float s4[8][9];
    __shared__ float s5[4][5];
    __shared__ float s6[2][3];
    int t = threadIdx.x;
    {
        int R = t >> 3, c8 = (t & 7) * 8;
        const float* base0 = &r1[(size_t)(BY * 64 + 2 * R) * n1 + BX * 64 + c8];
        const float* base1 = base0 + n1;
        float4 a0 = ((const float4*)base0)[0], a1 = ((const float4*)base0)[1];
        float4 b0 = ((const float4*)base1)[0], b1 = ((const float4*)base1)[1];
        float4 o;
        o.x = 0.25f * (a0.x + a0.y + b0.x + b0.y);
        o.y = 0.25f * (a0.z + a0.w + b0.z + b0.w);
        o.z = 0.25f * (a1.x + a1.y + b1.x + b1.y);
        o.w = 0.25f * (a1.z + a1.w + b1.z + b1.w);
        *(float4*)&r2[(size_t)(BY * 32 + R) * n2 + BX * 32 + (t & 7) * 4] = o;
        *(float4*)&s2[R][(t & 7) * 4] = o;
    }
    __syncthreads();
    {
        int y = t >> 4, x = t & 15;
        float v = 0.25f * (s2[2 * y][2 * x] + s2[2 * y][2 * x + 1] +
                           s2[2 * y + 1][2 * x] + s2[2 * y + 1][2 * x + 1]);
        r3[(size_t)(BY * 16 + y) * n3 + BX * 16 + x] = v;
        s3[y][x] = v;
    }
    __syncthreads();
    if (t < 64) {
        int y = t >> 3, x = t & 7;
        float v = 0.25f * (s3[2 * y][2 * x] + s3[2 * y][2 * x + 1] +
                           s3[2 * y + 1][2 * x] + s3[2 * y + 1][2 * x + 1]);
        r4[(size_t)(BY * 8 + y) * n4 + BX * 8 + x] = v;
        s4[y][x] = v;
    }
    __syncthreads();
    if (t < 16) {
        int y = t >> 2, x = t & 3;
        float v = 0.25f * (s4[2 * y][2 * x] + s4[2 * y][2 * x + 1] +
                           s4[2 * y + 1][2 * x] + s4[2 * y + 1][2 * x + 1]);
        r5[(size_t)(BY * 4 + y) * n5 + BX * 4 + x] = v;
        s5[y][x] = v;
    }
    __syncthreads();
    if (t < 4) {
        int y = t >> 1, x = t & 1;
        float v = 0.25f * (s5[2 * y][2 * x] + s5[2 * y][2 * x + 1] +
                           s5[2 * y + 1][2 * x] + s5[2 * y + 1][2 * x + 1]);
        r6[(size_t)(BY * 2 + y) * n6 + BX * 2 + x] = v;
        s6[y][x] = v;
    }
    __syncthreads();
    if (t == 0) {
        r7[(size_t)BY * n7 + BX] =
            0.25f * (s6[0][0] + s6[0][1] + s6[1][0] + s6[1][1]);
    }
}

// ---- fused coarse up-chain: r7..r3 -> e@512 (patch recompute per block) ----
__global__ __launch_bounds__(256) void coarse_up_kernel(
    const float* __restrict__ r7, const float* __restrict__ r6,
    const float* __restrict__ r5, const float* __restrict__ r4,
    const float* __restrict__ r3, const float* __restrict__ Ag,
    float* __restrict__ e512)
{
    int bx = blockIdx.x, by = blockIdx.y;  // 16x16 grid, 32x32 of e512 each
    int t = threadIdx.x;
    __shared__ float s7[32][33];
    __shared__ float s64[64][65];
    __shared__ float s128[11][12];
    __shared__ float s256[18][19];
    float Ac[3][3], inv;
    load_A(Ag, Ac, inv);
    for (int i = t; i < 1024; i += 256) s7[i >> 5][i & 31] = r7[i] * inv;
    __syncthreads();
    for (int i = t; i < 4096; i += 256) {
        int y = i >> 6, x = i & 63;
        float ctr = s7[y >> 1][x >> 1];
        float sm = 0.f;
#pragma unroll
        for (int dy = -1; dy <= 1; ++dy)
#pragma unroll
            for (int dx = -1; dx <= 1; ++dx) {
                if (dy == 0 && dx == 0) continue;
                int yy = y + dy, xx = x + dx;
                float pe = 0.f;
                if (yy >= 0 && yy < 64 && xx >= 0 && xx < 64) pe = s7[yy >> 1][xx >> 1];
                sm += Ac[dy + 1][dx + 1] * pe;
            }
        s64[y][x] = ctr - sm * inv + r6[i] * inv;
    }
    __syncthreads();
    int R1 = 8 * by - 2, C1 = 8 * bx - 2;
    if (t < 121) {
        int pr = t / 11, pc = t % 11;
        int gy = R1 + pr, gx = C1 + pc;
        if (gy >= 0 && gy < 128 && gx >= 0 && gx < 128) {
            float ctr = s64[gy >> 1][gx >> 1];
            float sm = 0.f;
#pragma unroll
            for (int dy = -1; dy <= 1; ++dy)
#pragma unroll
                for (int dx = -1; dx <= 1; ++dx) {
                    if (dy == 0 && dx == 0) continue;
                    int yy = gy + dy, xx = gx + dx;
                    float pe = 0.f;
                    if (yy >= 0 && yy < 128 && xx >= 0 && xx < 128) pe = s64[yy >> 1][xx >> 1];
                    sm += Ac[dy + 1][dx + 1] * pe;
                }
            s128[pr][pc] = ctr - sm * inv + r5[(size_t)gy * 128 + gx] * inv;
        }
    }
    __syncthreads();
    int R2l = 16 * by - 1, C2l = 16 * bx - 1;
    for (int i = t; i < 324; i += 256) {
        int pr = i / 18, pc = i % 18;
        int gy = R2l + pr, gx = C2l + pc;
        if (gy >= 0 && gy < 256 && gx >= 0 && gx < 256) {
            float ctr = s128[(gy >> 1) - R1][(gx >> 1) - C1];
            float sm = 0.f;
#pragma unroll
            for (int dy = -1; dy <= 1; ++dy)
#pragma unroll
                for (int dx = -1; dx <= 1; ++dx) {
                    if (dy == 0 && dx == 0) continue;
                    int yy = gy + dy, xx = gx + dx;
                    float pe = 0.f;
                    if (yy >= 0 && yy < 256 && xx >= 0 && xx < 256)
                        pe = s128[(yy >> 1) - R1][(xx >> 1) - C1];
                    sm += Ac[dy + 1][dx + 1] * pe;
                }
            s256[pr][pc] = ctr - sm * inv + r4[(size_t)gy * 256 + gx] * inv;
        }
    }
    __syncthreads();
#pragma unroll
    for (int k = 0; k < 4; ++k) {
        int idx = t + 256 * k;
        int y = 32 * by + (idx >> 5), x = 32 * bx + (idx & 31);
        float ctr = s256[(y >> 1) - R2l][(x >> 1) - C2l];
        float sm = 0.f;
#pragma unroll
        for (int dy = -1; dy <= 1; ++dy)
#pragma unroll
            for (int dx = -1; dx <= 1; ++dx) {
                if (dy == 0 && dx == 0) continue;
                int yy = y + dy, xx = x + dx;
                float pe = 0.f;
                if (yy >= 0 && yy < 512 && xx >= 0 && xx < 512)
                    pe = s256[(yy >> 1) - R2l][(xx >> 1) - C2l];
                sm += Ac[dy + 1][dx + 1] * pe;
            }
        e512[(size_t)y * 512 + x] = ctr - sm * inv + r3[(size_t)y * 512 + x] * inv;
    }
}

// ---- fused: e512 -> e1024 patch -> e2048 tile -> u update (+ minmax partials) ----
template <bool WANTMM>
__global__ __launch_bounds__(256) void final_fused_kernel(
    const float* __restrict__ u, const float* __restrict__ e512,
    const float* __restrict__ r2, const float* __restrict__ r1,
    const float* __restrict__ Ag, float* __restrict__ uo,
    float* __restrict__ partials)
{
    const int n = N;
    int bx = blockIdx.x, by = blockIdx.y;  // grid (32,256): u tile 128x16
    int t = threadIdx.x;
    __shared__ __align__(16) float su[18][132];
    __shared__ float s512[4][20];
    __shared__ float s1024[6][36];
    __shared__ float s2048[8][68];
    float Ac[3][3], inv;
    load_A(Ag, Ac, inv);
    int uy0 = 16 * by - 1, ux0 = 128 * bx - 1;
    bool safe = (uy0 >= 0) & (uy0 + 18 <= n) & (ux0 >= 0) & (ux0 + 130 <= n);
    if (safe) {
        const float* ub = &u[(size_t)uy0 * n + ux0];
        for (int i = t; i < 18 * 130; i += 256) {
            int row = i / 130, col = i - row * 130;
            su[row][col] = ub[(size_t)row * n + col];
        }
    } else {
        for (int i = t; i < 18 * 130; i += 256) {
            int row = i / 130, col = i - row * 130;
            int gy = uy0 + row, gx = ux0 + col;
            bool oy = (gy < 0) | (gy >= n);
            bool ox = (gx < 0) | (gx >= n);
            int cy = min(max(gy, 0), n - 1), cx = min(max(gx, 0), n - 1);
            su[row][col] = (oy & ox) ? 0.f : u[(size_t)cy * n + cx];
        }
    }
    int S5r = 2 * by - 1, S5c = 16 * bx - 1;
    if (t < 72) {
        int pr = t / 18, pc = t % 18;
        int gy = S5r + pr, gx = S5c + pc;
        if (gy >= 0 && gy < 512 && gx >= 0 && gx < 512)
            s512[pr][pc] = e512[(size_t)gy * 512 + gx];
    }
    __syncthreads();
    int R10 = 4 * by - 1, C10 = 32 * bx - 1;
    if (t < 204) {
        int pr = t / 34, pc = t % 34;
        int gy = R10 + pr, gx = C10 + pc;
        if (gy >= 0 && gy < 1024 && gx >= 0 && gx < 1024) {
            float ctr = s512[(gy >> 1) - S5r][(gx >> 1) - S5c];
            float sm = 0.f;
#pragma unroll
            for (int dy = -1; dy <= 1; ++dy)
#pragma unroll
                for (int dx = -1; dx <= 1; ++dx) {
                    if (dy == 0 && dx == 0) continue;
                    int yy = gy + dy, xx = gx + dx;
                    float pe = 0.f;
                    if (yy >= 0 && yy < 1024 && xx >= 0 && xx < 1024)
                        pe = s512[(yy >> 1) - S5r][(xx >> 1) - S5c];
                    sm += Ac[dy + 1][dx + 1] * pe;
                }
            s1024[pr][pc] = ctr - sm * inv + r2[(size_t)gy * 1024 + gx] * inv;
        }
    }
    __syncthreads();
    int E2r = 8 * by, E2c = 64 * bx;
    for (int i = t; i < 512; i += 256) {
        int pr = i >> 6, pc = i & 63;
        int gy = E2r + pr, gx = E2c + pc;
        float ctr = s1024[(gy >> 1) - R10][(gx >> 1) - C10];
        float sm = 0.f;
#pragma unroll
        for (int dy = -1; dy <= 1; ++dy)
#pragma unroll
            for (int dx = -1; dx <= 1; ++dx) {
                if (dy == 0 && dx == 0) continue;
                int yy = gy + dy, xx = gx + dx;
                float pe = 0.f;
                if (yy >= 0 && yy < 2048 && xx >= 0 && xx < 2048)
                    pe = s1024[(yy >> 1) - R10][(xx >> 1) - C10];
                sm += Ac[dy + 1][dx + 1] * pe;
            }
        s2048[pr][pc] = ctr - sm * inv + r1[(size_t)gy * 2048 + gx] * inv;
    }
    __syncthreads();
    int txx = t & 31, tyy = t >> 5;
    float mn = 3.402823466e+38f, mx = -3.402823466e+38f;
#pragma unroll
    for (int rr = 0; rr < 2; ++rr) {
        int yl = tyy + 8 * rr;
        int y = 16 * by + yl;
        float p[3][6];
#pragma unroll
        for (int a = 0; a < 3; ++a) {
            const float* rp = &su[yl + a][4 * txx];
            float4 v4 = *(const float4*)rp;
            float2 v2 = *(const float2*)(rp + 4);
            p[a][0] = v4.x; p[a][1] = v4.y; p[a][2] = v4.z;
            p[a][3] = v4.w; p[a][4] = v2.x; p[a][5] = v2.y;
        }
        float out[4];
#pragma unroll
        for (int cc = 0; cc < 4; ++cc) {
            float sm = 0.f;
#pragma unroll
            for (int i2 = 0; i2 < 3; ++i2)
#pragma unroll
                for (int j = 0; j < 3; ++j) sm += Ac[i2][j] * p[i2][cc + j];
            float e = s2048[yl >> 1][(4 * txx + cc) >> 1];
            out[cc] = p[1][cc + 1] - e - sm * inv;
        }
        *(float4*)&uo[(size_t)y * n + 128 * bx + 4 * txx] =
            make_float4(out[0], out[1], out[2], out[3]);
        if (WANTMM) {
            mn = fminf(mn, fminf(fminf(out[0], out[1]), fminf(out[2], out[3])));
            mx = fmaxf(mx, fmaxf(fmaxf(out[0], out[1]), fmaxf(out[2], out[3])));
        }
    }
    if (WANTMM) {
#pragma unroll
        for (int off = 32; off > 0; off >>= 1) {
            mn = fminf(mn, __shfl_down(mn, off));
            mx = fmaxf(mx, __shfl_down(mx, off));
        }
        __shared__ float smn[4], smx[4];
        int lane = t & 63, wv = t >> 6;
        if (lane == 0) { smn[wv] = mn; smx[wv] = mx; }
        __syncthreads();
        if (t == 0) {
            mn = smn[0]; mx = smx[0];
            for (int wq = 1; wq < 4; ++wq) { mn = fminf(mn, smn[wq]); mx = fmaxf(mx, smx[wq]); }
            int bid = by * 32 + bx;
            partials[2 * bid] = mn;
            partials[2 * bid + 1] = mx;
        }
    }
}

__global__ __launch_bounds__(1024) void minmax_final_kernel(
    const float* __restrict__ partials, float* __restrict__ mm)
{
    float mn = 3.402823466e+38f, mx = -3.402823466e+38f;
    for (int i = threadIdx.x; i < 8192; i += 1024) {
        mn = fminf(mn, partials[2 * i]);
        mx = fmaxf(mx, partials[2 * i + 1]);
    }
#pragma unroll
    for (int off = 32; off > 0; off >>= 1) {
        mn = fminf(mn, __shfl_down(mn, off));
        mx = fmaxf(mx, __shfl_down(mx, off));
    }
    __shared__ float smn[16], smx[16];
    int lane = threadIdx.x & 63, wv = threadIdx.x >> 6;
    if (lane == 0) { smn[wv] = mn; smx[wv] = mx; }
    __syncthreads();
    if (threadIdx.x == 0) {
        mn = smn[0]; mx = smx[0];
        for (int w = 1; w < 16; ++w) { mn = fminf(mn, smn[w]); mx = fmaxf(mx, smx[w]); }
        mm[0] = mn;
        mm[1] = mx;
    }
}

__global__ __launch_bounds__(256) void normalize_kernel(
    float* __restrict__ u, const float* __restrict__ mm)
{
    size_t i = ((size_t)blockIdx.x * 256 + threadIdx.x) * 4;
    float mn = mm[0];
    float sc = 1.0f / (mm[1] - mm[0]);
    float4 v = *(float4*)&u[i];
    v.x = (v.x - mn) * sc;
    v.y = (v.y - mn) * sc;
    v.z = (v.z - mn) * sc;
    v.w = (v.w - mn) * sc;
    *(float4*)&u[i] = v;
}

extern "C" void kernel_launch(void* const* d_in, const int* in_sizes, int n_in,
                              void* d_out, int out_size, void* d_ws, size_t ws_size,
                              hipStream_t stream)
{
    const float* A  = (const float*)d_in[0];
    const float* u0 = (const float*)d_in[1];
    float* uout = (float*)d_out;
    float* ws = (float*)d_ws;

    size_t off = 0;
    float* r1 = ws + off; off += 2048ull * 2048;
    float* r2 = ws + off; off += 1024ull * 1024;
    float* r3 = ws + off; off += 512ull * 512;
    float* r4 = ws + off; off += 256ull * 256;
    float* r5 = ws + off; off += 128ull * 128;
    float* r6 = ws + off; off += 64ull * 64;
    float* r7 = ws + off; off += 32ull * 32;
    float* e5 = ws + off; off += 512ull * 512;
    float* uA = ws + off; off += 4096ull * 4096;
    float* partials = ws + off; off += 16384;
    float* mm = ws + off; off += 2;

    dim3 blk(256);
    for (int it = 0; it < 4; ++it) {
        const float* us = (it == 0) ? u0 : ((it == 2) ? uout : uA);
        float* dst = (it & 1) ? uout : uA;
        smooth_restrict_kernel<<<dim3(32, 256), blk, 0, stream>>>(us, A, r1);
        multirestrict_kernel<<<dim3(32, 32), blk, 0, stream>>>(r1, r2, r3, r4, r5, r6, r7);
        coarse_up_kernel<<<dim3(16, 16), blk, 0, stream>>>(r7, r6, r5, r4, r3, A, e5);
        if (it == 3)
            final_fused_kernel<true><<<dim3(32, 256), blk, 0, stream>>>(us, e5, r2, r1, A, dst, partials);
        else
            final_fused_kernel<false><<<dim3(32, 256), blk, 0, stream>>>(us, e5, r2, r1, A, dst, partials);
    }
    minmax_final_kernel<<<1, 1024, 0, stream>>>(partials, mm);
    normalize_kernel<<<16384, 256, 0, stream>>>(uout, mm);
}